// Round 3
// baseline (1010.069 us; speedup 1.0000x reference)
//
#include <hip/hip_runtime.h>

// Problem constants (fixed by reference): B=4, S=2048 -> N_TOK=8192; IN=OUT=4096; POOLS=128; top_k=2.
#define K_DIM  4096
#define N_OUT  4096
#define N_TOK  8192
#define N_POOL 128

typedef __bf16 bf16x8 __attribute__((ext_vector_type(8)));
typedef float  f32x4  __attribute__((ext_vector_type(4)));
typedef unsigned short u16x8 __attribute__((ext_vector_type(8)));

__device__ __forceinline__ unsigned short f2bf(float f) {
    union { float f; unsigned u; } v; v.f = f;
    unsigned r = v.u + 0x7fffu + ((v.u >> 16) & 1u);   // RNE
    return (unsigned short)(r >> 16);
}

// ---------------- kernel 1: fp32 -> bf16 bulk convert (used for w0 and x) ----------------
__global__ __launch_bounds__(256) void k_convert(const float* __restrict__ src,
                                                 unsigned short* __restrict__ dst) {
    size_t base = ((size_t)blockIdx.x * 256 + threadIdx.x) * 8;
    float4 a = *(const float4*)(src + base);
    float4 b = *(const float4*)(src + base + 4);
    u16x8 r;
    r[0] = f2bf(a.x); r[1] = f2bf(a.y); r[2] = f2bf(a.z); r[3] = f2bf(a.w);
    r[4] = f2bf(b.x); r[5] = f2bf(b.y); r[6] = f2bf(b.z); r[7] = f2bf(b.w);
    *(u16x8*)(dst + base) = r;
}

// ---------------- kernel 1b: u [OUT,POOLS] -> uT [POOLS,OUT] ----------------
__global__ __launch_bounds__(256) void k_transpose_u(const float* __restrict__ u,
                                                     float* __restrict__ uT) {
    __shared__ float t[32][65];
    const int o0 = blockIdx.x * 64, p0 = blockIdx.y * 32;
    const int tid = threadIdx.x;
#pragma unroll
    for (int it = 0; it < 8; it++) {
        int o = (tid >> 5) + it * 8;
        t[tid & 31][o] = u[(size_t)(o0 + o) * N_POOL + p0 + (tid & 31)];
    }
    __syncthreads();
#pragma unroll
    for (int it = 0; it < 8; it++) {
        int p = (tid >> 6) + it * 4;
        uT[(size_t)(p0 + p) * N_OUT + o0 + (tid & 63)] = t[p][tid & 63];
    }
}

// ---------------- kernel 1c: wr [POOLS,K] -> wrT [K,POOLS] (k-major for the router) ----------
__global__ __launch_bounds__(256) void k_transpose_wr(const float* __restrict__ wr,
                                                      float* __restrict__ wrT) {
    __shared__ float t[32][33];
    const int k0 = blockIdx.x * 32, p0 = blockIdx.y * 32;
    const int tid = threadIdx.x;
#pragma unroll
    for (int it = 0; it < 4; it++) {
        int p = (tid >> 5) + it * 8;
        int k = tid & 31;
        t[k][p] = wr[(size_t)(p0 + p) * K_DIM + k0 + k];
    }
    __syncthreads();
#pragma unroll
    for (int it = 0; it < 4; it++) {
        int k = (tid >> 5) + it * 8;
        int p = tid & 31;
        wrT[(size_t)(k0 + k) * N_POOL + p0 + p] = t[k][p];
    }
}

// ---------------- kernel 2: router — barrier-free, LDS-free streaming ----------------
// 512 blocks x 16 tokens. Wave w owns tokens w*4..w*4+3. Thread = (tg: 2 tokens) x (pg: 4 pools).
// x loads are half-wave broadcasts (same address across 32 lanes); wrT rows are 512 B
// contiguous slices (L1/L2-resident, waves kept converged by a light sync every 256 k).
#define RTOK 16

__global__ __launch_bounds__(256) void k_router(const float* __restrict__ x,
                                                const float* __restrict__ wrT,
                                                const float* __restrict__ svh,
                                                int* __restrict__ idxp,
                                                float* __restrict__ dotp) {
    const int tid  = threadIdx.x;
    const int w    = tid >> 6, lane = tid & 63;
    const int pg   = lane & 31, tg = lane >> 5;
    const int m0   = blockIdx.x * RTOK;
    const int tokA = m0 + w * 4 + tg * 2;

    const float* xA = x + (size_t)tokA * K_DIM;
    const float* xB = xA + K_DIM;
    const float* wp = wrT + pg * 4;

    float a0[4] = {0.f,0.f,0.f,0.f}, a1[4] = {0.f,0.f,0.f,0.f};

    for (int kc = 0; kc < K_DIM; kc += 256) {
        for (int k0 = kc; k0 < kc + 256; k0 += 8) {
            float4 xa[2], xb4[2], wv[8];
#pragma unroll
            for (int q = 0; q < 2; q++) {
                xa[q]  = *(const float4*)(xA + k0 + q * 4);
                xb4[q] = *(const float4*)(xB + k0 + q * 4);
            }
#pragma unroll
            for (int j = 0; j < 8; j++)
                wv[j] = *(const float4*)(wp + (size_t)(k0 + j) * N_POOL);
#pragma unroll
            for (int q = 0; q < 2; q++)
#pragma unroll
                for (int j = 0; j < 4; j++) {
                    float av = (&xa[q].x)[j], bv = (&xb4[q].x)[j];
                    float4 wj = wv[q * 4 + j];
                    a0[0] += av * wj.x; a0[1] += av * wj.y;
                    a0[2] += av * wj.z; a0[3] += av * wj.w;
                    a1[0] += bv * wj.x; a1[1] += bv * wj.y;
                    a1[2] += bv * wj.z; a1[3] += bv * wj.w;
                }
        }
        __syncthreads();   // convergence only: keeps the block's waves L1-coherent on wrT
    }

    // local top-2 over this thread's 4 pools, per token (strict '>' == jax tie rule)
    float v1[2], v2[2]; int i1[2], i2[2];
#pragma unroll
    for (int t = 0; t < 2; t++) {
        const float* ac = t ? a1 : a0;
        float b1 = -3.4e38f, b2 = -3.4e38f; int j1 = 0, j2 = 0;
#pragma unroll
        for (int q = 0; q < 4; q++) {
            float v = ac[q]; int idx = pg * 4 + q;
            if (v > b1)      { b2 = b1; j2 = j1; b1 = v; j1 = idx; }
            else if (v > b2) { b2 = v;  j2 = idx; }
        }
        v1[t] = b1; i1[t] = j1; v2[t] = b2; i2[t] = j2;
    }
    // butterfly merge across the 32-lane half (equal value -> lower index wins)
#pragma unroll
    for (int off = 1; off < 32; off <<= 1) {
#pragma unroll
        for (int t = 0; t < 2; t++) {
            float o1 = __shfl_xor(v1[t], off), o2 = __shfl_xor(v2[t], off);
            int  oi1 = __shfl_xor(i1[t], off), oi2 = __shfl_xor(i2[t], off);
            bool owin = (o1 > v1[t]) || (o1 == v1[t] && oi1 < i1[t]);
            float n1, n2; int ni1, ni2;
            if (owin) {
                n1 = o1; ni1 = oi1;
                bool sw = (v1[t] > o2) || (v1[t] == o2 && i1[t] < oi2);
                n2 = sw ? v1[t] : o2; ni2 = sw ? i1[t] : oi2;
            } else {
                n1 = v1[t]; ni1 = i1[t];
                bool sw = (o1 > v2[t]) || (o1 == v2[t] && oi1 < i2[t]);
                n2 = sw ? o1 : v2[t]; ni2 = sw ? oi1 : i2[t];
            }
            v1[t] = n1; i1[t] = ni1; v2[t] = n2; i2[t] = ni2;
        }
    }
    if ((lane & 31) == 0) {
#pragma unroll
        for (int t = 0; t < 2; t++) {
            idxp[(size_t)(tokA + t) * 2 + 0] = i1[t];
            idxp[(size_t)(tokA + t) * 2 + 1] = i2[t];
        }
    }

    // svh dots for the wave's own 4 tokens (fp32 x, L1/L2-warm; svh L2-resident)
#pragma unroll
    for (int s = 0; s < 4; s++) {
        const int src = (s >> 1) * 32;
        const int e0 = __shfl((s & 1) ? i1[1] : i1[0], src);
        const int e1 = __shfl((s & 1) ? i2[1] : i2[0], src);
        const float* xr = x   + (size_t)(m0 + w * 4 + s) * K_DIM;
        const float* p0 = svh + (size_t)e0 * K_DIM;
        const float* p1 = svh + (size_t)e1 * K_DIM;
        float d0 = 0.f, d1 = 0.f;
#pragma unroll 4
        for (int it = 0; it < 16; it++) {
            const int off = (it * 64 + lane) * 4;
            float4 xv = *(const float4*)(xr + off);
            float4 q0 = *(const float4*)(p0 + off);
            float4 q1 = *(const float4*)(p1 + off);
            d0 += xv.x*q0.x + xv.y*q0.y + xv.z*q0.z + xv.w*q0.w;
            d1 += xv.x*q1.x + xv.y*q1.y + xv.z*q1.z + xv.w*q1.w;
        }
#pragma unroll
        for (int off = 32; off > 0; off >>= 1) {
            d0 += __shfl_down(d0, off);
            d1 += __shfl_down(d1, off);
        }
        if (lane == 0) {
            dotp[(size_t)(m0 + w * 4 + s) * 2 + 0] = d0;
            dotp[(size_t)(m0 + w * 4 + s) * 2 + 1] = d1;
        }
    }
}

// ---------------- kernel 3: bf16 MFMA GEMM + fused bias/expert epilogue (unchanged) ----------
// C tile 128x128, BK=64, 4 waves each owning a 64x64 quadrant (4x4 of 16x16x32 MFMA).
// XOR source-swizzle at 16B-chunk granularity kills the fragment-read bank conflicts
// (round 2: SQ_LDS_BANK_CONFLICT 1.0e8 -> 0, MfmaUtil 14.8 -> 37.8).
__global__ __launch_bounds__(256) void k_gemm(const unsigned short* __restrict__ xb,
                                              const unsigned short* __restrict__ w0b,
                                              const float* __restrict__ b0,
                                              const float* __restrict__ uT,
                                              const int* __restrict__ idxp,
                                              const float* __restrict__ dotp,
                                              float* __restrict__ out) {
    __shared__ unsigned short Als[128 * 64];   // 16 KB
    __shared__ unsigned short Bls[128 * 64];   // 16 KB

    const int tid  = threadIdx.x;
    const int lane = tid & 63;
    const int wv   = tid >> 6;
    const int wm   = wv & 1, wn = wv >> 1;
    const int lrow = lane & 15, lquad = lane >> 4;
    const size_t m0 = (size_t)blockIdx.y * 128;   // token tile
    const size_t n0 = (size_t)blockIdx.x * 128;   // out-feature tile

    const int srow   = tid >> 3;
    const int xchunk = (tid & 7) ^ (srow & 7);    // swizzled 16B chunk within the row
    const unsigned short* ag = xb  + (m0 + srow) * K_DIM + xchunk * 8;
    const unsigned short* bg = w0b + (n0 + srow) * K_DIM + xchunk * 8;
    unsigned short* al = Als + tid * 8;
    unsigned short* bl = Bls + tid * 8;

    f32x4 acc[4][4] = {};

    for (int k0 = 0; k0 < K_DIM; k0 += 64) {
        __syncthreads();
#pragma unroll
        for (int i = 0; i < 4; i++) {
            __builtin_amdgcn_global_load_lds(
                (const __attribute__((address_space(1))) void*)(ag + (size_t)i * 32 * K_DIM + k0),
                (__attribute__((address_space(3))) void*)(al + i * 2048), 16, 0, 0);
            __builtin_amdgcn_global_load_lds(
                (const __attribute__((address_space(1))) void*)(bg + (size_t)i * 32 * K_DIM + k0),
                (__attribute__((address_space(3))) void*)(bl + i * 2048), 16, 0, 0);
        }
        __syncthreads();
#pragma unroll
        for (int ks = 0; ks < 2; ks++) {
            bf16x8 af[4], bfr[4];
#pragma unroll
            for (int t = 0; t < 4; t++)
                af[t] = *(const bf16x8*)&Als[(wm * 64 + t * 16 + lrow) * 64 +
                                             (((ks * 4 + lquad) ^ (lrow & 7)) * 8)];
#pragma unroll
            for (int t = 0; t < 4; t++)
                bfr[t] = *(const bf16x8*)&Bls[(wn * 64 + t * 16 + lrow) * 64 +
                                              (((ks * 4 + lquad) ^ (lrow & 7)) * 8)];
#pragma unroll
            for (int mt = 0; mt < 4; mt++)
#pragma unroll
                for (int nt = 0; nt < 4; nt++)
                    acc[mt][nt] = __builtin_amdgcn_mfma_f32_16x16x32_bf16(af[mt], bfr[nt], acc[mt][nt], 0, 0, 0);
        }
    }

    // epilogue: C/D layout col=lane&15, row=(lane>>4)*4+reg (m89-verified)
#pragma unroll
    for (int mt = 0; mt < 4; mt++) {
        const size_t rb = m0 + wm * 64 + mt * 16 + lquad * 4;
#pragma unroll
        for (int r = 0; r < 4; r++) {
            const size_t gm = rb + r;
            const int e0 = idxp[gm * 2 + 0], e1 = idxp[gm * 2 + 1];
            const float dd0 = dotp[gm * 2 + 0], dd1 = dotp[gm * 2 + 1];
#pragma unroll
            for (int nt = 0; nt < 4; nt++) {
                const size_t gn = n0 + wn * 64 + nt * 16 + lrow;
                float vv = acc[mt][nt][r] + b0[gn]
                         + dd0 * uT[(size_t)e0 * N_OUT + gn] + dd1 * uT[(size_t)e1 * N_OUT + gn];
                out[gm * N_OUT + gn] = vv;
            }
        }
    }
}

extern "C" void kernel_launch(void* const* d_in, const int* in_sizes, int n_in,
                              void* d_out, int out_size, void* d_ws, size_t ws_size,
                              hipStream_t stream) {
    const float* x   = (const float*)d_in[0];  // [8192, 4096]
    const float* w0  = (const float*)d_in[1];  // [4096, 4096]
    const float* b0  = (const float*)d_in[2];  // [4096]
    const float* wr  = (const float*)d_in[3];  // [128, 4096]
    const float* u   = (const float*)d_in[4];  // [4096, 128]
    const float* svh = (const float*)d_in[5];  // [128, 4096]
    float* out = (float*)d_out;

    // workspace layout (~100.1 MiB total)
    char* ws = (char*)d_ws;
    unsigned short* xb  = (unsigned short*)ws;                       // 67108864 B
    unsigned short* w0b = (unsigned short*)(ws + 67108864);          // 33554432 B
    int*   idxp = (int*)(ws + 100663296);                            // 65536 B
    float* dotp = (float*)(ws + 100728832);                          // 65536 B
    float* uTp  = (float*)(ws + 100794368);                          // 2097152 B
    float* wrTp = (float*)(ws + 102891520);                          // 2097152 B

    k_transpose_wr<<<dim3(K_DIM / 32, N_POOL / 32), dim3(256), 0, stream>>>(wr, wrTp);
    k_router<<<dim3(N_TOK / RTOK), dim3(256), 0, stream>>>(x, wrTp, svh, idxp, dotp);
    k_convert<<<dim3((N_TOK * K_DIM) / 2048), dim3(256), 0, stream>>>(x, xb);
    k_convert<<<dim3((N_OUT * K_DIM) / 2048), dim3(256), 0, stream>>>(w0, w0b);
    k_transpose_u<<<dim3(N_OUT / 64, N_POOL / 32), dim3(256), 0, stream>>>(u, uTp);
    k_gemm<<<dim3(N_OUT / 128, N_TOK / 128), dim3(256), 0, stream>>>(xb, w0b, b0, uTp, idxp, dotp, out);
}